// Round 1
// baseline (572.771 us; speedup 1.0000x reference)
//
#include <hip/hip_runtime.h>
#include <math.h>

// ---------------- problem constants ----------------
#define NT 512      // N_TARGET
#define NF 1024     // N_FEAT
#define NCAT 1536
#define NFUNC 32
#define BATCHSZ 16

// output layout (float elements, concatenated in return order)
constexpr int O_MEM  = 0;          // 16384*512
constexpr int O_TMEM = 8388608;    // 16384 (written as float)
constexpr int O_FEAT = 8404992;    // 16384*1024
constexpr int O_ARE  = 25182208;   // 32*512
constexpr int O_AIM  = 25198592;
constexpr int O_FREQ = 25214976;   // 32
constexpr int O_RP   = 25215008;   // 1536*512
constexpr int O_BIAS = 26001440;   // 512
constexpr int O_FM   = 26001952;   // 1024
constexpr int O_AGR  = 26002976;   // 32*512
constexpr int O_AGI  = 26019360;
constexpr int O_FGR  = 26035744;   // 32
constexpr int O_RPG  = 26035776;   // 1536*512

// ws layout (floats)
constexpr int W_LR    = 0;
constexpr int W_ANORM = 2;   // [2] per-batch
constexpr int W_RNORM = 4;   // [2]
constexpr int W_GFR   = 8;   // [2*32]
constexpr int W_TB    = 72;  // [16]
constexpr int W_C     = 96;    // [16*32]
constexpr int W_S     = 608;   // [16*32]
constexpr int W_CATZ  = 1120;  // [16*512]
constexpr int W_CATX  = 9312;  // [16*1024]
constexpr int W_GR    = 25696; // [16*512]
constexpr int W_G     = 33888; // [16*512]
constexpr int W_AGRE  = 42080; // [32*512]
constexpr int W_AGIM  = 58464; // [32*512]

constexpr float MM_LR = 0.03f;
constexpr float AMP_DECAY = 0.01f;
constexpr float MOM = 0.85f;
constexpr float INV_SQRT_NF = 0.17677669529663687f; // 1/sqrt(32)
constexpr float TWO_PI = 6.283185307179586f;

__device__ __forceinline__ float sgnf(float x) {
    return (x > 0.f) ? 1.f : ((x < 0.f) ? -1.f : 0.f);
}

__device__ __forceinline__ float wave_reduce(float v) {
#pragma unroll
    for (int o = 32; o > 0; o >>= 1) v += __shfl_down(v, o, 64);
    return v; // lane 0 holds sum
}

// ---------------- K0: copies + init ----------------
__global__ void k_init(const int* tptr, const int* dsptr,
                       const float* x, const float* z,
                       const float* memory, const int* t_memory, const float* feat_memory,
                       const float* amp_re, const float* amp_im, const float* freq,
                       const float* res_proj, const float* feat_mean, const float* bias,
                       const float* amp_grad_re, const float* amp_grad_im,
                       const float* freq_grad, const float* res_proj_grad,
                       float* out, float* ws)
{
    const int ds = *dsptr;
    const long long total = 6705584LL; // float4-units of work
    for (long long u0 = (long long)blockIdx.x * blockDim.x + threadIdx.x; u0 < total;
         u0 += (long long)gridDim.x * blockDim.x) {
        long long u = u0;
        if (u < 2097152) {                       // memory copy (row ds <- z)
            int f = (int)u; int row = f >> 7;    // 128 float4 per 512-row
            float4 v = (row == ds) ? ((const float4*)z)[f & 127]
                                   : ((const float4*)memory)[f];
            ((float4*)(out + O_MEM))[f] = v;
        } else if ((u -= 2097152) < 4194304) {   // feat_memory copy (row ds <- x)
            int f = (int)u; int row = f >> 8;    // 256 float4 per 1024-row
            float4 v = (row == ds) ? ((const float4*)x)[f & 255]
                                   : ((const float4*)feat_memory)[f];
            ((float4*)(out + O_FEAT))[f] = v;
        } else if ((u -= 4194304) < 196608) {    // res_proj copy
            int f = (int)u;
            ((float4*)(out + O_RP))[f] = ((const float4*)res_proj)[f];
        } else if ((u -= 196608) < 196608) {     // res_proj_grad copy
            int f = (int)u;
            ((float4*)(out + O_RPG))[f] = ((const float4*)res_proj_grad)[f];
        } else if ((u -= 196608) < 16384) {      // amp_{re,im}, amp_grad_{re,im}
            int f = (int)u; int which = f >> 12; int idx = f & 4095;
            const float4* src = which == 0 ? (const float4*)amp_re
                              : which == 1 ? (const float4*)amp_im
                              : which == 2 ? (const float4*)amp_grad_re
                                           : (const float4*)amp_grad_im;
            float4* dst = which == 0 ? (float4*)(out + O_ARE)
                        : which == 1 ? (float4*)(out + O_AIM)
                        : which == 2 ? (float4*)(out + O_AGR)
                                     : (float4*)(out + O_AGI);
            dst[idx] = src[idx];
        } else if ((u -= 16384) < 4096) {        // t_memory -> float (row ds <- t)
            int f = (int)u; int4 iv = ((const int4*)t_memory)[f];
            int e = f * 4; int tt = *tptr;
            float* o = out + O_TMEM + e;
            o[0] = (e + 0 == ds) ? (float)tt : (float)iv.x;
            o[1] = (e + 1 == ds) ? (float)tt : (float)iv.y;
            o[2] = (e + 2 == ds) ? (float)tt : (float)iv.z;
            o[3] = (e + 3 == ds) ? (float)tt : (float)iv.w;
        } else if ((u -= 4096) < 128) {          // bias = (bias*ds_new + z)/(ds_new+1)
            int f = (int)u;
            float4 b = ((const float4*)bias)[f]; float4 zz = ((const float4*)z)[f];
            float n = (float)(ds + 1), d = (float)(ds + 2);
            float4 r2; r2.x = (b.x*n+zz.x)/d; r2.y = (b.y*n+zz.y)/d;
            r2.z = (b.z*n+zz.z)/d; r2.w = (b.w*n+zz.w)/d;
            ((float4*)(out + O_BIAS))[f] = r2;
        } else if ((u -= 128) < 256) {           // feat_mean
            int f = (int)u;
            float4 m = ((const float4*)feat_mean)[f]; float4 xx = ((const float4*)x)[f];
            float n = (float)(ds + 1), d = (float)(ds + 2);
            float4 r2; r2.x = (m.x*n+xx.x)/d; r2.y = (m.y*n+xx.y)/d;
            r2.z = (m.z*n+xx.z)/d; r2.w = (m.w*n+xx.w)/d;
            ((float4*)(out + O_FM))[f] = r2;
        } else if ((u -= 256) < 16) {            // freq + freq_grad copies
            int f = (int)u;
            if (f < 8) ((float4*)(out + O_FREQ))[f] = ((const float4*)freq)[f];
            else       ((float4*)(out + O_FGR))[f - 8] = ((const float4*)freq_grad)[f - 8];
        } else {                                 // ws init: lr + zero accumulators
            u -= 16;
            int q = (int)u;
            if (q == 0) {
                ws[W_LR] = (float)pow(0.977, (double)(ds + 1));
                ws[1] = 0.f; ws[2] = 0.f; ws[3] = 0.f;
            } else {
                float4 zv; zv.x = zv.y = zv.z = zv.w = 0.f;
                ((float4*)ws)[q] = zv;   // zeros ws[4..128): rnorm, gfr, tb
            }
        }
    }
}

// ---------------- per-batch: forward + g_r ----------------
// grid 128 x 64: block (i = bb>>3, jc = bb&7) handles j in [jc*64, jc*64+64)
__global__ __launch_bounds__(64) void k_fwd(int b, const int* ts, const float* cf,
                                            float* out, float* ws)
{
    __shared__ float c_l[32], s_l[32], z_row[NT], catz_l[NT], catx_l[NF];
    const int i = blockIdx.x >> 3, jc = blockIdx.x & 7, tid = threadIdx.x;
    const int bi = ts[b * BATCHSZ + i];
    const float* tmem = out + O_TMEM;
    const float* mem  = out + O_MEM;
    const float* feat = out + O_FEAT;
    const float* are  = out + O_ARE;
    const float* aim  = out + O_AIM;
    const float* fq   = out + O_FREQ;
    const float* rp   = out + O_RP;
    const float* bias = out + O_BIAS;
    const float* fm   = out + O_FM;
    const float tb = tmem[bi];
    if (tid < 32) {
        float f  = fq[tid];
        float th = tanhf(f);
        float u  = cf[tid] + 2.f * th;
        float sg = 1.f / (1.f + expf(-u));
        float fr = 0.5f * sg;
        float ph = TWO_PI * tb * fr;
        float cv = cosf(ph), sv = sinf(ph);
        c_l[tid] = cv; s_l[tid] = sv;
        if (jc == 0) {
            ws[W_C + i*32 + tid] = cv; ws[W_S + i*32 + tid] = sv;
            if (tid == 0) ws[W_TB + i] = tb;
        }
    }
    __syncthreads();
    for (int q = tid; q < NT; q += 64) {
        float acc = 0.f;
#pragma unroll
        for (int k = 0; k < 32; ++k)
            acc += c_l[k] * are[k*NT + q] - s_l[k] * aim[k*NT + q];
        float cz = acc * INV_SQRT_NF;   // z_ - bias
        catz_l[q] = cz;
        z_row[q]  = cz + bias[q];
        if (jc == 0) ws[W_CATZ + i*NT + q] = cz;
    }
    for (int p = tid; p < NF; p += 64) {
        float cx = feat[bi*NF + p] - fm[p];
        catx_l[p] = cx;
        if (jc == 0) ws[W_CATX + i*NF + p] = cx;
    }
    __syncthreads();
    const int j = jc*64 + tid;
    float r0 = 0.f, r1 = 0.f, r2 = 0.f, r3 = 0.f;
#pragma unroll 8
    for (int p = 0; p < NF; p += 4) {
        r0 += catx_l[p+0] * rp[(p+0)*NT + j];
        r1 += catx_l[p+1] * rp[(p+1)*NT + j];
        r2 += catx_l[p+2] * rp[(p+2)*NT + j];
        r3 += catx_l[p+3] * rp[(p+3)*NT + j];
    }
#pragma unroll 8
    for (int q = 0; q < NT; q += 4) {
        r0 += catz_l[q+0] * rp[(NF+q+0)*NT + j];
        r1 += catz_l[q+1] * rp[(NF+q+1)*NT + j];
        r2 += catz_l[q+2] * rp[(NF+q+2)*NT + j];
        r3 += catz_l[q+3] * rp[(NF+q+3)*NT + j];
    }
    float r  = (r0 + r1) + (r2 + r3);
    float zb = mem[bi*NT + j];
    float zj = z_row[j];
    float s1 = sgnf(zj - zb);
    float ar = fabsf(r) + 1.f;
    float resid = r / ar;
    float z2 = zj + resid;
    float g  = sgnf(z2 - zb) * (MM_LR / 16.f) / (ar * ar);
    ws[W_GR + i*NT + j] = g;
    ws[W_G  + i*NT + j] = s1 * (1.f / 16.f);   // direct part of dL/dz_
}

// ---------------- per-batch: G residual part + rnorm ----------------
// blocks [0,2048): one wave per G element (coalesced 512-dot)
// blocks [2048,5120): rg = cat^T g_r, accumulate rnorm_sq
__global__ void k_gr(int b, float* out, float* ws)
{
    __shared__ float red[4];
    const float* rp = out + O_RP;
    const int bb = blockIdx.x, tid = threadIdx.x;
    if (bb < 2048) {
        int wid = tid >> 6, lane = tid & 63;
        int e = bb*4 + wid;
        int i = e >> 9, j = e & 511;
        const float* grow = ws + W_GR + i*NT;
        const float* rrow = rp + (NF + j)*NT;
        float acc = 0.f;
#pragma unroll
        for (int l = lane; l < NT; l += 64) acc += grow[l] * rrow[l];
        acc = wave_reduce(acc);
        if (lane == 0) ws[W_G + e] += acc;     // unique owner, no race
    } else {
        int e = (bb - 2048)*256 + tid;
        int p = e >> 9, j = e & 511;
        float rg = 0.f;
#pragma unroll
        for (int i2 = 0; i2 < 16; ++i2) {
            float cat = (p < NF) ? ws[W_CATX + i2*NF + p]
                                 : ws[W_CATZ + i2*NT + (p - NF)];
            rg += cat * ws[W_GR + i2*NT + j];
        }
        float v = wave_reduce(rg * rg);
        if ((tid & 63) == 0) red[tid >> 6] = v;
        __syncthreads();
        if (tid == 0) atomicAdd(&ws[W_RNORM + b], red[0]+red[1]+red[2]+red[3]);
    }
}

// ---------------- per-batch: amp grads + freq grad partials ----------------
// blocks [0,64): ag_re/ag_im + anorm;  blocks [64,192): one wave per (i,k) pair
__global__ void k_ag(int b, float* out, float* ws)
{
    __shared__ float red[4];
    const float* are = out + O_ARE;
    const float* aim = out + O_AIM;
    const int bb = blockIdx.x, tid = threadIdx.x;
    if (bb < 64) {
        int e = bb*256 + tid;
        int k = e >> 9, j = e & 511;
        float gre = 0.f, gim = 0.f;
#pragma unroll
        for (int i2 = 0; i2 < 16; ++i2) {
            float G = ws[W_G + i2*NT + j];
            gre += G * ws[W_C + i2*32 + k];
            gim += G * ws[W_S + i2*32 + k];
        }
        float re = are[e], im = aim[e];
        float aa = sqrtf(re*re + im*im);
        float dec = AMP_DECAY / (2.f * aa * sqrtf(aa));   // d sqrt(|a|)/da
        float agr =  gre * INV_SQRT_NF + re * dec;
        float agi = -gim * INV_SQRT_NF + im * dec;
        ws[W_AGRE + e] = agr;
        ws[W_AGIM + e] = agi;
        float v = wave_reduce(agr*agr + agi*agi);
        if ((tid & 63) == 0) red[tid >> 6] = v;
        __syncthreads();
        if (tid == 0) atomicAdd(&ws[W_ANORM + b], red[0]+red[1]+red[2]+red[3]);
    } else {
        int wid = tid >> 6, lane = tid & 63;
        int pair = (bb - 64)*4 + wid;      // 512 pairs
        int i = pair >> 5, k = pair & 31;
        float ck = ws[W_C + i*32 + k], sk = ws[W_S + i*32 + k];
        float acc = 0.f;
#pragma unroll
        for (int j = lane; j < NT; j += 64)
            acc += ws[W_G + i*NT + j] * (-sk * are[k*NT + j] - ck * aim[k*NT + j]);
        acc = wave_reduce(acc);
        if (lane == 0)
            atomicAdd(&ws[W_GFR + b*32 + k], acc * TWO_PI * ws[W_TB + i] * INV_SQRT_NF);
    }
}

// ---------------- per-batch: parameter updates ----------------
// blocks [0,64): amp;  block 64: freq;  blocks [65,3137): res_proj (recompute rg)
__global__ void k_upd(int b, const float* cf, float* out, float* ws)
{
    const float lr = ws[W_LR];
    const int bb = blockIdx.x, tid = threadIdx.x;
    if (bb < 64) {
        int e = bb*256 + tid;
        float anorm = sqrtf(ws[W_ANORM + b]) + 1.f;
        float* agr_o = out + O_AGR; float* agi_o = out + O_AGI;
        float* are_o = out + O_ARE; float* aim_o = out + O_AIM;
        float mr = agr_o[e]*MOM + ws[W_AGRE + e]/anorm;
        agr_o[e] = mr; are_o[e] -= mr*lr;
        float mi = agi_o[e]*MOM + ws[W_AGIM + e]/anorm;
        agi_o[e] = mi; aim_o[e] -= mi*lr;
    } else if (bb == 64) {
        if (tid < 64) {
            float fg = 0.f;
            float* fq_o  = out + O_FREQ;
            float* fgr_o = out + O_FGR;
            float th = 0.f;
            if (tid < 32) {
                float f = fq_o[tid];
                th = tanhf(f);
                float u  = cf[tid] + 2.f*th;
                float sg = 1.f / (1.f + expf(-u));
                fg = ws[W_GFR + b*32 + tid] * sg*(1.f-sg)*(1.f-th*th);
            }
            float t2 = fg*fg;
#pragma unroll
            for (int o = 32; o > 0; o >>= 1) t2 += __shfl_down(t2, o, 64);
            float tot = __shfl(t2, 0, 64);
            if (tid < 32) {
                float fnorm = sqrtf(tot) + 1.f;
                float m = fgr_o[tid]*MOM + fg/fnorm;
                fgr_o[tid] = m;
                fq_o[tid] -= m*lr;
            }
        }
    } else {
        int e = (bb - 65)*256 + tid;
        int p = e >> 9, j = e & 511;
        float rg = 0.f;
#pragma unroll
        for (int i2 = 0; i2 < 16; ++i2) {
            float cat = (p < NF) ? ws[W_CATX + i2*NF + p]
                                 : ws[W_CATZ + i2*NT + (p - NF)];
            rg += cat * ws[W_GR + i2*NT + j];   // same order as k_gr -> identical fp
        }
        float rnorm = sqrtf(ws[W_RNORM + b]) + 1.f;
        float* rpg_o = out + O_RPG; float* rp_o = out + O_RP;
        float m = rpg_o[e]*MOM + rg/rnorm;
        rpg_o[e] = m; rp_o[e] -= m*lr;
    }
}

extern "C" void kernel_launch(void* const* d_in, const int* in_sizes, int n_in,
                              void* d_out, int out_size, void* d_ws, size_t ws_size,
                              hipStream_t stream)
{
    const int*   t            = (const int*)d_in[0];
    const int*   ds           = (const int*)d_in[1];
    const int*   ts           = (const int*)d_in[2];
    const float* x            = (const float*)d_in[3];
    const float* z            = (const float*)d_in[4];
    const float* memory       = (const float*)d_in[5];
    const int*   t_memory     = (const int*)d_in[6];
    const float* feat_memory  = (const float*)d_in[7];
    const float* amp_re       = (const float*)d_in[8];
    const float* amp_im       = (const float*)d_in[9];
    const float* freq         = (const float*)d_in[10];
    const float* cf           = (const float*)d_in[11];
    const float* res_proj     = (const float*)d_in[12];
    const float* feat_mean    = (const float*)d_in[13];
    const float* bias         = (const float*)d_in[14];
    const float* amp_grad_re  = (const float*)d_in[15];
    const float* amp_grad_im  = (const float*)d_in[16];
    const float* freq_grad    = (const float*)d_in[17];
    const float* res_proj_grad= (const float*)d_in[18];
    float* out = (float*)d_out;
    float* ws  = (float*)d_ws;

    k_init<<<8192, 256, 0, stream>>>(t, ds, x, z, memory, t_memory, feat_memory,
                                     amp_re, amp_im, freq, res_proj, feat_mean, bias,
                                     amp_grad_re, amp_grad_im, freq_grad, res_proj_grad,
                                     out, ws);
    for (int b = 0; b < 2; ++b) {
        k_fwd<<<128,  64,  0, stream>>>(b, ts, cf, out, ws);
        k_gr <<<5120, 256, 0, stream>>>(b, out, ws);
        k_ag <<<192,  256, 0, stream>>>(b, out, ws);
        k_upd<<<3137, 256, 0, stream>>>(b, cf, out, ws);
    }
}

// Round 2
// 376.869 us; speedup vs baseline: 1.5198x; 1.5198x over previous
//
#include <hip/hip_runtime.h>
#include <math.h>

// ---------------- problem constants ----------------
#define NT 512      // N_TARGET
#define NF 1024     // N_FEAT
#define NFUNC 32
#define BATCHSZ 16

// output layout (float elements, concatenated in return order)
constexpr int O_MEM  = 0;          // 16384*512
constexpr int O_TMEM = 8388608;    // 16384 (written as float)
constexpr int O_FEAT = 8404992;    // 16384*1024
constexpr int O_ARE  = 25182208;   // 32*512
constexpr int O_AIM  = 25198592;
constexpr int O_FREQ = 25214976;   // 32
constexpr int O_RP   = 25215008;   // 1536*512
constexpr int O_BIAS = 26001440;   // 512
constexpr int O_FM   = 26001952;   // 1024
constexpr int O_AGR  = 26002976;   // 32*512
constexpr int O_AGI  = 26019360;
constexpr int O_FGR  = 26035744;   // 32
constexpr int O_RPG  = 26035776;   // 1536*512

// ws layout (floats)
constexpr int W_LR    = 0;
constexpr int W_ANORM = 2;   // [2] per-batch
constexpr int W_RNORM = 4;   // [2]
constexpr int W_GFR   = 8;   // [2*32]
constexpr int W_TB    = 72;  // [16]
constexpr int W_C     = 96;    // [16*32]
constexpr int W_S     = 608;   // [16*32]
constexpr int W_CATZ  = 1120;  // [16*512]
constexpr int W_CATX  = 9312;  // [16*1024]
constexpr int W_GR    = 25696; // [16*512]
constexpr int W_G     = 33888; // [16*512]
constexpr int W_AGRE  = 42080; // [32*512]
constexpr int W_AGIM  = 58464; // [32*512]
constexpr int W_RPART = 74848; // [16*8192] split-K partials (~824KB ws total)

constexpr float MM_LR = 0.03f;
constexpr float AMP_DECAY = 0.01f;
constexpr float MOM = 0.85f;
constexpr float INV_SQRT_NF = 0.17677669529663687f; // 1/sqrt(32)
constexpr float TWO_PI = 6.283185307179586f;

constexpr int NCOPY = 192;          // copy-helper blocks appended to every kernel
constexpr long long U_TOTAL = 6295552LL; // float4 units: mem 2097152 + feat 4194304 + tmem 4096

__device__ __forceinline__ float sgnf(float x) {
    return (x > 0.f) ? 1.f : ((x < 0.f) ? -1.f : 0.f);
}

__device__ __forceinline__ float wave_reduce(float v) {
#pragma unroll
    for (int o = 32; o > 0; o >>= 1) v += __shfl_down(v, o, 64);
    return v; // lane 0 holds sum
}

// ------------- background copy: slice [cbase, cbase+ccnt) of U_TOTAL -------------
__device__ __forceinline__ void copy_role(int rb, int cbase, int ccnt,
    const int* __restrict__ tptr, const int* __restrict__ dsptr,
    const float* __restrict__ x, const float* __restrict__ z,
    const float* __restrict__ memory, const int* __restrict__ t_memory,
    const float* __restrict__ feat_memory, float* __restrict__ out)
{
    const int dsv = *dsptr;
    const int tt  = *tptr;
    const int nthr = NCOPY * 256;
    for (int q = rb * 256 + (int)threadIdx.x; q * 4 < ccnt; q += nthr) {
#pragma unroll
        for (int w = 0; w < 4; ++w) {
            int rel = q * 4 + w;
            if (rel >= ccnt) break;
            int u = cbase + rel;
            if (u < 2097152) {               // memory (row ds <- z)
                int row = u >> 7;
                float4 v = (row == dsv) ? ((const float4*)z)[u & 127]
                                        : ((const float4*)memory)[u];
                ((float4*)(out + O_MEM))[u] = v;
            } else if (u < 6291456) {        // feat_memory (row ds <- x)
                int f = u - 2097152;
                int row = f >> 8;
                float4 v = (row == dsv) ? ((const float4*)x)[f & 255]
                                        : ((const float4*)feat_memory)[f];
                ((float4*)(out + O_FEAT))[f] = v;
            } else {                          // t_memory -> float (row ds <- t)
                int f = u - 6291456;
                int4 iv = ((const int4*)t_memory)[f];
                int e = f * 4;
                float* o = out + O_TMEM + e;
                o[0] = (e + 0 == dsv) ? (float)tt : (float)iv.x;
                o[1] = (e + 1 == dsv) ? (float)tt : (float)iv.y;
                o[2] = (e + 2 == dsv) ? (float)tt : (float)iv.z;
                o[3] = (e + 3 == dsv) ? (float)tt : (float)iv.w;
            }
        }
    }
}

#define COPY_ARGS const int* __restrict__ tptr, const int* __restrict__ dsptr,            \
                  const float* __restrict__ x, const float* __restrict__ z,               \
                  const float* __restrict__ memory, const int* __restrict__ t_memory,     \
                  const float* __restrict__ feat_memory, int cbase, int ccnt
#define COPY_PASS tptr, dsptr, x, z, memory, t_memory, feat_memory

// ---------------- A: c/s/tb + catz + catx (one block per sample i) ----------------
__global__ __launch_bounds__(256) void k_fwd_a(int b, const int* __restrict__ ts,
    const float* __restrict__ cf,
    const float* __restrict__ are_src, const float* __restrict__ aim_src,
    const float* __restrict__ fq_src, const float* __restrict__ fm_in,
    float* __restrict__ out, float* __restrict__ ws, COPY_ARGS)
{
    const int bb = blockIdx.x, tid = threadIdx.x;
    if (bb >= 16) { copy_role(bb - 16, cbase, ccnt, COPY_PASS, out); return; }
    __shared__ float c_l[32], s_l[32];
    const int i = bb;
    const int dsv = *dsptr;
    const int bi = ts[b * BATCHSZ + i];
    if (tid < 32) {
        float f  = fq_src[tid];
        float th = tanhf(f);
        float u  = cf[tid] + 2.f * th;
        float sg = 1.f / (1.f + expf(-u));
        float fr = 0.5f * sg;
        float tb = (bi == dsv) ? (float)(*tptr) : (float)t_memory[bi];
        float ph = TWO_PI * tb * fr;
        float cv = cosf(ph), sv = sinf(ph);
        c_l[tid] = cv; s_l[tid] = sv;
        ws[W_C + i*32 + tid] = cv; ws[W_S + i*32 + tid] = sv;
        if (tid == 0) ws[W_TB + i] = tb;
    }
    if (i == 0) {  // per-batch accumulator init
        if (tid == 64) ws[W_ANORM + b] = 0.f;
        if (tid == 65) ws[W_RNORM + b] = 0.f;
        if (tid == 66 && b == 0) ws[W_LR] = (float)pow(0.977, (double)(dsv + 1));
        if (tid >= 96 && tid < 128) ws[W_GFR + b*32 + tid - 96] = 0.f;
    }
    __syncthreads();
#pragma unroll
    for (int qq = 0; qq < 2; ++qq) {
        int q = tid + qq * 256;
        float acc = 0.f;
#pragma unroll
        for (int k = 0; k < 32; ++k)
            acc += c_l[k] * are_src[k*NT + q] - s_l[k] * aim_src[k*NT + q];
        ws[W_CATZ + i*NT + q] = acc * INV_SQRT_NF;   // z_ - bias
    }
    const float nn = (float)(dsv + 1), dd = (float)(dsv + 2);
#pragma unroll
    for (int pp = 0; pp < 4; ++pp) {
        int p = tid + pp * 256;
        float fmv = (fm_in[p] * nn + x[p]) / dd;
        float xv  = (bi == dsv) ? x[p] : feat_memory[bi*NF + p];
        ws[W_CATX + i*NF + p] = xv - fmv;
    }
}

// ---------------- B: split-K matmul r[i][j] partials (block = (i, s-chunk)) ----------------
__global__ __launch_bounds__(256) void k_fwd_b(const float* __restrict__ rp_src,
    float* __restrict__ out, float* __restrict__ ws, COPY_ARGS)
{
    const int bb = blockIdx.x, tid = threadIdx.x;
    if (bb >= 256) { copy_role(bb - 256, cbase, ccnt, COPY_PASS, out); return; }
    const int i = bb >> 4, s = bb & 15;
    __shared__ float cat[96];
    if (tid < 96) {
        int p = s * 96 + tid;
        cat[tid] = (p < NF) ? ws[W_CATX + i*NF + p] : ws[W_CATZ + i*NT + p - NF];
    }
    __syncthreads();
    const int j = tid;
    const float* rpb = rp_src + (size_t)s * 96 * NT;
    float a0 = 0.f, a1 = 0.f, b0 = 0.f, b1 = 0.f;
#pragma unroll 8
    for (int p = 0; p < 96; p += 2) {
        float c0 = cat[p], c1 = cat[p + 1];
        a0 += c0 * rpb[p*NT + j];
        a1 += c0 * rpb[p*NT + j + 256];
        b0 += c1 * rpb[(p+1)*NT + j];
        b1 += c1 * rpb[(p+1)*NT + j + 256];
    }
    ws[W_RPART + s*8192 + i*NT + j]       = a0 + b0;
    ws[W_RPART + s*8192 + i*NT + j + 256] = a1 + b1;
}

// ---------------- C: epilogue — sum partials, g_r, G-direct (+bias/fm on b=0) ----------------
__global__ __launch_bounds__(256) void k_eplg(int b, const int* __restrict__ ts,
    const float* __restrict__ bias_in, const float* __restrict__ fm_in,
    float* __restrict__ out, float* __restrict__ ws, COPY_ARGS)
{
    const int bb = blockIdx.x, tid = threadIdx.x;
    if (bb >= 32) { copy_role(bb - 32, cbase, ccnt, COPY_PASS, out); return; }
    const int e = bb * 256 + tid;
    const int i = e >> 9, j = e & 511;
    const int dsv = *dsptr;
    float r = 0.f;
#pragma unroll
    for (int s = 0; s < 16; ++s) r += ws[W_RPART + s*8192 + e];
    const float nn = (float)(dsv + 1), dd = (float)(dsv + 2);
    float bn = (bias_in[j] * nn + z[j]) / dd;
    float zj = ws[W_CATZ + e] + bn;
    const int bi = ts[b * BATCHSZ + i];
    float zb = (bi == dsv) ? z[j] : memory[bi*NT + j];
    float s1 = sgnf(zj - zb);
    float ar = fabsf(r) + 1.f;
    float z2 = zj + r / ar;
    float g  = sgnf(z2 - zb) * (MM_LR / 16.f) / (ar * ar);
    ws[W_GR + e] = g;
    ws[W_G  + e] = s1 * (1.f / 16.f);
    if (b == 0) {
        if (e < 512)  out[O_BIAS + e] = bn;  // i==0 here, so bn is bias_new[e]
        if (e < 1024) out[O_FM + e] = (fm_in[e] * nn + x[e]) / dd;
    }
}

// ---------------- D: G residual part + rg-norm ----------------
__global__ __launch_bounds__(256) void k_gr(int b, const float* __restrict__ rp_src,
    float* __restrict__ out, float* __restrict__ ws, COPY_ARGS)
{
    __shared__ float red[4];
    const int bb = blockIdx.x, tid = threadIdx.x;
    if (bb >= 5120) { copy_role(bb - 5120, cbase, ccnt, COPY_PASS, out); return; }
    if (bb < 2048) {      // one wave per G element: dot(g_r[i,:], rp[NF+j,:])
        int wid = tid >> 6, lane = tid & 63;
        int e = bb*4 + wid;
        int i = e >> 9, j = e & 511;
        const float* grow = ws + W_GR + i*NT;
        const float* rrow = rp_src + (size_t)(NF + j) * NT;
        float acc = 0.f;
#pragma unroll
        for (int l = lane; l < NT; l += 64) acc += grow[l] * rrow[l];
        acc = wave_reduce(acc);
        if (lane == 0) ws[W_G + e] += acc;
    } else {              // rg = cat^T g_r; accumulate rnorm^2
        int e = (bb - 2048)*256 + tid;
        int p = e >> 9, j = e & 511;
        float rg = 0.f;
#pragma unroll
        for (int i2 = 0; i2 < 16; ++i2) {
            float cat = (p < NF) ? ws[W_CATX + i2*NF + p]
                                 : ws[W_CATZ + i2*NT + (p - NF)];
            rg += cat * ws[W_GR + i2*NT + j];
        }
        float v = wave_reduce(rg * rg);
        if ((tid & 63) == 0) red[tid >> 6] = v;
        __syncthreads();
        if (tid == 0) atomicAdd(&ws[W_RNORM + b], red[0]+red[1]+red[2]+red[3]);
    }
}

// ---------------- E: amp grads + anorm + freq-grad partials ----------------
__global__ __launch_bounds__(256) void k_ag(int b,
    const float* __restrict__ are_src, const float* __restrict__ aim_src,
    float* __restrict__ out, float* __restrict__ ws, COPY_ARGS)
{
    __shared__ float red[4];
    const int bb = blockIdx.x, tid = threadIdx.x;
    if (bb >= 192) { copy_role(bb - 192, cbase, ccnt, COPY_PASS, out); return; }
    if (bb < 64) {
        int e = bb*256 + tid;
        int k = e >> 9;
        float gre = 0.f, gim = 0.f;
#pragma unroll
        for (int i2 = 0; i2 < 16; ++i2) {
            float G = ws[W_G + i2*NT + (e & 511)];
            gre += G * ws[W_C + i2*32 + k];
            gim += G * ws[W_S + i2*32 + k];
        }
        float re = are_src[e], im = aim_src[e];
        float aa = sqrtf(re*re + im*im);
        float dec = AMP_DECAY / (2.f * aa * sqrtf(aa));
        float agr =  gre * INV_SQRT_NF + re * dec;
        float agi = -gim * INV_SQRT_NF + im * dec;
        ws[W_AGRE + e] = agr;
        ws[W_AGIM + e] = agi;
        float v = wave_reduce(agr*agr + agi*agi);
        if ((tid & 63) == 0) red[tid >> 6] = v;
        __syncthreads();
        if (tid == 0) atomicAdd(&ws[W_ANORM + b], red[0]+red[1]+red[2]+red[3]);
    } else {
        int wid = tid >> 6, lane = tid & 63;
        int pair = (bb - 64)*4 + wid;      // 512 = 16 i x 32 k
        int i = pair >> 5, k = pair & 31;
        float ck = ws[W_C + i*32 + k], sk = ws[W_S + i*32 + k];
        float acc = 0.f;
#pragma unroll
        for (int j = lane; j < NT; j += 64)
            acc += ws[W_G + i*NT + j] * (-sk * are_src[k*NT + j] - ck * aim_src[k*NT + j]);
        acc = wave_reduce(acc);
        if (lane == 0)
            atomicAdd(&ws[W_GFR + b*32 + k], acc * TWO_PI * ws[W_TB + i] * INV_SQRT_NF);
    }
}

// ---------------- F: parameter updates ----------------
__global__ __launch_bounds__(256) void k_upd(int b, const float* __restrict__ cf,
    const float* __restrict__ are_src, const float* __restrict__ aim_src,
    const float* __restrict__ agr_src, const float* __restrict__ agi_src,
    const float* __restrict__ fq_src,  const float* __restrict__ fgr_src,
    const float* __restrict__ rp_src,  const float* __restrict__ rpg_src,
    float* __restrict__ out, float* __restrict__ ws, COPY_ARGS)
{
    const int bb = blockIdx.x, tid = threadIdx.x;
    if (bb >= 3137) { copy_role(bb - 3137, cbase, ccnt, COPY_PASS, out); return; }
    const float lr = ws[W_LR];
    if (bb < 64) {
        int e = bb*256 + tid;
        float anorm = sqrtf(ws[W_ANORM + b]) + 1.f;
        float mr = agr_src[e]*MOM + ws[W_AGRE + e]/anorm;
        out[O_AGR + e] = mr; out[O_ARE + e] = are_src[e] - mr*lr;
        float mi = agi_src[e]*MOM + ws[W_AGIM + e]/anorm;
        out[O_AGI + e] = mi; out[O_AIM + e] = aim_src[e] - mi*lr;
    } else if (bb == 64) {
        if (tid < 64) {
            float fg = 0.f, th = 0.f;
            if (tid < 32) {
                float f = fq_src[tid];
                th = tanhf(f);
                float u  = cf[tid] + 2.f*th;
                float sg = 1.f / (1.f + expf(-u));
                fg = ws[W_GFR + b*32 + tid] * sg*(1.f-sg)*(1.f-th*th);
            }
            float t2 = fg*fg;
#pragma unroll
            for (int o = 32; o > 0; o >>= 1) t2 += __shfl_down(t2, o, 64);
            float tot = __shfl(t2, 0, 64);
            if (tid < 32) {
                float fnorm = sqrtf(tot) + 1.f;
                float m = fgr_src[tid]*MOM + fg/fnorm;
                out[O_FGR + tid] = m;
                out[O_FREQ + tid] = fq_src[tid] - m*lr;
            }
        }
    } else {
        int e = (bb - 65)*256 + tid;
        int p = e >> 9, j = e & 511;
        float rg = 0.f;
#pragma unroll
        for (int i2 = 0; i2 < 16; ++i2) {
            float cat = (p < NF) ? ws[W_CATX + i2*NF + p]
                                 : ws[W_CATZ + i2*NT + (p - NF)];
            rg += cat * ws[W_GR + i2*NT + j];   // same order as k_gr -> identical fp
        }
        float rnorm = sqrtf(ws[W_RNORM + b]) + 1.f;
        float m = rpg_src[e]*MOM + rg/rnorm;
        out[O_RPG + e] = m; out[O_RP + e] = rp_src[e] - m*lr;
    }
}

extern "C" void kernel_launch(void* const* d_in, const int* in_sizes, int n_in,
                              void* d_out, int out_size, void* d_ws, size_t ws_size,
                              hipStream_t stream)
{
    const int*   t            = (const int*)d_in[0];
    const int*   dsp          = (const int*)d_in[1];
    const int*   ts           = (const int*)d_in[2];
    const float* x            = (const float*)d_in[3];
    const float* z            = (const float*)d_in[4];
    const float* memory       = (const float*)d_in[5];
    const int*   t_memory     = (const int*)d_in[6];
    const float* feat_memory  = (const float*)d_in[7];
    const float* amp_re       = (const float*)d_in[8];
    const float* amp_im       = (const float*)d_in[9];
    const float* freq         = (const float*)d_in[10];
    const float* cf           = (const float*)d_in[11];
    const float* res_proj     = (const float*)d_in[12];
    const float* feat_mean    = (const float*)d_in[13];
    const float* bias         = (const float*)d_in[14];
    const float* amp_grad_re  = (const float*)d_in[15];
    const float* amp_grad_im  = (const float*)d_in[16];
    const float* freq_grad    = (const float*)d_in[17];
    const float* res_proj_grad= (const float*)d_in[18];
    float* out = (float*)d_out;
    float* ws  = (float*)d_ws;

    const float* ARE[2] = { amp_re,        out + O_ARE };
    const float* AIM[2] = { amp_im,        out + O_AIM };
    const float* AGR[2] = { amp_grad_re,   out + O_AGR };
    const float* AGI[2] = { amp_grad_im,   out + O_AGI };
    const float* FQ [2] = { freq,          out + O_FREQ };
    const float* FGR[2] = { freq_grad,     out + O_FGR };
    const float* RP [2] = { res_proj,      out + O_RP };
    const float* RPG[2] = { res_proj_grad, out + O_RPG };

    // 12 copy slices (multiples of 4 except the tail)
    const int per = 524628;
    int base = 0, k = 0;
    auto nxt = [&](int& cb, int& cc) {
        cb = base;
        cc = (k == 11) ? (int)(U_TOTAL - base) : per;
        base += cc; ++k;
    };
    int cb, cc;
    for (int b = 0; b < 2; ++b) {
        nxt(cb, cc);
        k_fwd_a<<<16 + NCOPY, 256, 0, stream>>>(b, ts, cf, ARE[b], AIM[b], FQ[b],
            feat_mean, out, ws, t, dsp, x, z, memory, t_memory, feat_memory, cb, cc);
        nxt(cb, cc);
        k_fwd_b<<<256 + NCOPY, 256, 0, stream>>>(RP[b], out, ws,
            t, dsp, x, z, memory, t_memory, feat_memory, cb, cc);
        nxt(cb, cc);
        k_eplg<<<32 + NCOPY, 256, 0, stream>>>(b, ts, bias, feat_mean, out, ws,
            t, dsp, x, z, memory, t_memory, feat_memory, cb, cc);
        nxt(cb, cc);
        k_gr<<<5120 + NCOPY, 256, 0, stream>>>(b, RP[b], out, ws,
            t, dsp, x, z, memory, t_memory, feat_memory, cb, cc);
        nxt(cb, cc);
        k_ag<<<192 + NCOPY, 256, 0, stream>>>(b, ARE[b], AIM[b], out, ws,
            t, dsp, x, z, memory, t_memory, feat_memory, cb, cc);
        nxt(cb, cc);
        k_upd<<<3137 + NCOPY, 256, 0, stream>>>(b, cf, ARE[b], AIM[b], AGR[b], AGI[b],
            FQ[b], FGR[b], RP[b], RPG[b], out, ws,
            t, dsp, x, z, memory, t_memory, feat_memory, cb, cc);
    }
}